// Round 4
// baseline (455.015 us; speedup 1.0000x reference)
//
#include <hip/hip_runtime.h>
#include <hip/hip_bf16.h>

typedef short bf16x8 __attribute__((ext_vector_type(8)));
typedef float f32x16 __attribute__((ext_vector_type(16)));

#define NB 8
#define NPTS 8192
#define NSET (NB * NPTS)

static __device__ __forceinline__ short bfbits(float x) {
    __hip_bfloat16 h = __float2bfloat16(x);  // RNE
    return *reinterpret_cast<short*>(&h);
}
static __device__ __forceinline__ float bfval(float x) {
    __hip_bfloat16 h = __float2bfloat16(x);
    return __bfloat162float(h);
}

// Per point, emit K=16 bf16 row-features (A) and col-features (B) so that
// dot(A_t, B_p) = |t|^2 + |p|^2 - 2 t.p  (hi/lo bf16 split, err ~2^-16 rel).
__global__ __launch_bounds__(256) void pack2_kernel(
    const float* __restrict__ target, const float* __restrict__ pred,
    short* __restrict__ tA, short* __restrict__ tB,
    short* __restrict__ pA, short* __restrict__ pB) {
    int gi = blockIdx.x * 256 + threadIdx.x;
    int second = gi >= NSET;
    int i = second ? gi - NSET : gi;
    const float* pts = second ? pred : target;
    short* A = second ? pA : tA;
    short* B = second ? pB : tB;

    float x = pts[3 * i + 0], y = pts[3 * i + 1], z = pts[3 * i + 2];
    float n2 = x * x + y * y + z * z;

    float xh = bfval(x), yh = bfval(y), zh = bfval(z), nh = bfval(n2);
    short xhb = bfbits(x), yhb = bfbits(y), zhb = bfbits(z), nhb = bfbits(n2);
    short xlb = bfbits(x - xh), ylb = bfbits(y - yh), zlb = bfbits(z - zh), nlb = bfbits(n2 - nh);
    short one = bfbits(1.0f);
    short mxh = bfbits(-2.0f * xh), myh = bfbits(-2.0f * yh), mzh = bfbits(-2.0f * zh);
    short mxl = bfbits(-2.0f * __bfloat162float(*(__hip_bfloat16*)&xlb));
    short myl = bfbits(-2.0f * __bfloat162float(*(__hip_bfloat16*)&ylb));
    short mzl = bfbits(-2.0f * __bfloat162float(*(__hip_bfloat16*)&zlb));

    // A k=0..15: [1,1,n2h,n2l, xh,xh,xl, yh,yh,yl, zh,zh,zl, 0,0,0]
    bf16x8 a0, a1, b0, b1;
    a0[0] = one; a0[1] = one; a0[2] = nhb; a0[3] = nlb;
    a0[4] = xhb; a0[5] = xhb; a0[6] = xlb; a0[7] = yhb;
    a1[0] = yhb; a1[1] = ylb; a1[2] = zhb; a1[3] = zhb;
    a1[4] = zlb; a1[5] = 0;   a1[6] = 0;   a1[7] = 0;
    // B k=0..15: [n2h,n2l,1,1, -2xh,-2xl,-2xh, -2yh,-2yl,-2yh, -2zh,-2zl,-2zh, 0,0,0]
    b0[0] = nhb; b0[1] = nlb; b0[2] = one; b0[3] = one;
    b0[4] = mxh; b0[5] = mxl; b0[6] = mxh; b0[7] = myh;
    b1[0] = myl; b1[1] = myh; b1[2] = mzh; b1[3] = mzl;
    b1[4] = mzh; b1[5] = 0;   b1[6] = 0;   b1[7] = 0;

    *reinterpret_cast<bf16x8*>(&A[(size_t)i * 16])     = a0;
    *reinterpret_cast<bf16x8*>(&A[(size_t)i * 16 + 8]) = a1;
    *reinterpret_cast<bf16x8*>(&B[(size_t)i * 16])     = b0;
    *reinterpret_cast<bf16x8*>(&B[(size_t)i * 16 + 8]) = b1;
}

// Grid 2048: direction x 8 batches x 32 row-groups x 4 col-quarters.
// Each wave: 2 row-frags (64 rows), 64 col-tiles in 32 pairs; min3-fold into
// 32 register row-min accumulators; butterfly + atomicMin epilogue.
// 8 blocks/CU (=32 waves/CU) for latency hiding.
__global__ __launch_bounds__(256, 8) void chamfer_mfma_kernel(
    const short* __restrict__ targA, const short* __restrict__ targB,
    const short* __restrict__ predA, const short* __restrict__ predB,
    int* __restrict__ dist1, int* __restrict__ dist2)
{
    const int bid  = blockIdx.x;
    const int pass = bid >> 10;
    const int r10  = bid & 1023;
    const int b    = r10 >> 7;
    const int rest = r10 & 127;
    const int rowgrp = rest >> 2;       // 32 groups of 256 rows
    const int colq   = rest & 3;        // 4 quarters of 2048 cols
    const int wave = threadIdx.x >> 6;
    const int lane = threadIdx.x & 63;
    const int l31  = lane & 31, h = lane >> 5;

    const short* Af = pass ? predA : targA;
    const short* Bf = pass ? targB : predB;
    int* out = pass ? dist2 : dist1;

    const int row0 = rowgrp * 256 + wave * 64;
    const short* abase = Af + ((size_t)(b * NPTS + row0 + l31)) * 16 + h * 8;
    bf16x8 a0 = *reinterpret_cast<const bf16x8*>(abase);
    bf16x8 a1 = *reinterpret_cast<const bf16x8*>(abase + 32 * 16);

    const short* bptr = Bf + ((size_t)(b * NPTS + colq * 2048 + l31)) * 16 + h * 8;

    float acc0[16], acc1[16];
#pragma unroll
    for (int r = 0; r < 16; ++r) { acc0[r] = 3.4e38f; acc1[r] = 3.4e38f; }

    const f32x16 z = {0.f,0.f,0.f,0.f, 0.f,0.f,0.f,0.f, 0.f,0.f,0.f,0.f, 0.f,0.f,0.f,0.f};

    bf16x8 bA = *reinterpret_cast<const bf16x8*>(bptr);
    bf16x8 bB = *reinterpret_cast<const bf16x8*>(bptr + 512);

    for (int it = 0; it < 31; ++it) {
        bf16x8 nA = *reinterpret_cast<const bf16x8*>(bptr + 1024);
        bf16x8 nB = *reinterpret_cast<const bf16x8*>(bptr + 1536);

        f32x16 c0a = __builtin_amdgcn_mfma_f32_32x32x16_bf16(a0, bA, z, 0, 0, 0);
        f32x16 c0b = __builtin_amdgcn_mfma_f32_32x32x16_bf16(a0, bB, z, 0, 0, 0);
#pragma unroll
        for (int r = 0; r < 16; ++r)
            acc0[r] = fminf(acc0[r], fminf(c0a[r], c0b[r]));  // -> v_min3_f32

        f32x16 c1a = __builtin_amdgcn_mfma_f32_32x32x16_bf16(a1, bA, z, 0, 0, 0);
        f32x16 c1b = __builtin_amdgcn_mfma_f32_32x32x16_bf16(a1, bB, z, 0, 0, 0);
#pragma unroll
        for (int r = 0; r < 16; ++r)
            acc1[r] = fminf(acc1[r], fminf(c1a[r], c1b[r]));

        bA = nA; bB = nB;
        bptr += 1024;
    }
    {   // peeled last pair (no prefetch)
        f32x16 c0a = __builtin_amdgcn_mfma_f32_32x32x16_bf16(a0, bA, z, 0, 0, 0);
        f32x16 c0b = __builtin_amdgcn_mfma_f32_32x32x16_bf16(a0, bB, z, 0, 0, 0);
#pragma unroll
        for (int r = 0; r < 16; ++r)
            acc0[r] = fminf(acc0[r], fminf(c0a[r], c0b[r]));
        f32x16 c1a = __builtin_amdgcn_mfma_f32_32x32x16_bf16(a1, bA, z, 0, 0, 0);
        f32x16 c1b = __builtin_amdgcn_mfma_f32_32x32x16_bf16(a1, bB, z, 0, 0, 0);
#pragma unroll
        for (int r = 0; r < 16; ++r)
            acc1[r] = fminf(acc1[r], fminf(c1a[r], c1b[r]));
    }

    // butterfly min over the 32 cols held in each half's lanes
#pragma unroll
    for (int r = 0; r < 16; ++r) {
        float v0 = acc0[r], v1 = acc1[r];
#pragma unroll
        for (int s = 1; s < 32; s <<= 1) {
            v0 = fminf(v0, __shfl_xor(v0, s));
            v1 = fminf(v1, __shfl_xor(v1, s));
        }
        acc0[r] = v0; acc1[r] = v1;
    }

    if (l31 == 0) {
        int* ob = out + b * NPTS + row0;
#pragma unroll
        for (int r = 0; r < 16; ++r) {
            int rr = (r & 3) + 8 * (r >> 2) + 4 * h;  // verified C layout (m74/m101)
            // clamp >=0 so positive-float bit order == int order for atomicMin
            atomicMin(&ob[rr],      __float_as_int(fmaxf(acc0[r], 0.0f)));
            atomicMin(&ob[32 + rr], __float_as_int(fmaxf(acc1[r], 0.0f)));
        }
    }
}

__global__ __launch_bounds__(256) void reduce_kernel(const int* __restrict__ mins,
                                                     float* __restrict__ out) {
    int i = blockIdx.x * 256 + threadIdx.x;
    float v = __int_as_float(mins[i]) * (1.0f / (float)NSET);
#pragma unroll
    for (int o = 32; o > 0; o >>= 1) v += __shfl_down(v, o);
    if ((threadIdx.x & 63) == 0) atomicAdd(out, v);
}

extern "C" void kernel_launch(void* const* d_in, const int* in_sizes, int n_in,
                              void* d_out, int out_size, void* d_ws, size_t ws_size,
                              hipStream_t stream) {
    const float* pred   = (const float*)d_in[0];   // [8,8192,3]
    const float* target = (const float*)d_in[1];   // [8,8192,3]
    float* out = (float*)d_out;

    char* ws = (char*)d_ws;
    int* dist1 = (int*)ws;                           // 65536 ints (float bits)
    int* dist2 = dist1 + NSET;                       // 65536 ints
    short* tA = (short*)(ws + (size_t)2 * NSET * 4); // each 2 MB
    short* tB = tA + (size_t)NSET * 16;
    short* pA = tB + (size_t)NSET * 16;
    short* pB = pA + (size_t)NSET * 16;

    hipMemsetAsync(dist1, 0x7F, (size_t)2 * NSET * 4, stream);  // +huge float
    hipMemsetAsync(out, 0, sizeof(float), stream);

    pack2_kernel<<<2 * NSET / 256, 256, 0, stream>>>(target, pred, tA, tB, pA, pB);

    chamfer_mfma_kernel<<<2048, 256, 0, stream>>>(tA, tB, pA, pB, dist1, dist2);

    reduce_kernel<<<2 * NSET / 256, 256, 0, stream>>>(dist1, out);
}

// Round 5
// 93.930 us; speedup vs baseline: 4.8442x; 4.8442x over previous
//
#include <hip/hip_runtime.h>
#include <hip/hip_bf16.h>

typedef short bf16x8 __attribute__((ext_vector_type(8)));
typedef float f32x16 __attribute__((ext_vector_type(16)));

#define NB 8
#define NPTS 8192
#define NSET (NB * NPTS)

static __device__ __forceinline__ short bfbits(float x) {
    __hip_bfloat16 h = __float2bfloat16(x);  // RNE
    return *reinterpret_cast<short*>(&h);
}
static __device__ __forceinline__ float bfval(float x) {
    __hip_bfloat16 h = __float2bfloat16(x);
    return __bfloat162float(h);
}

// Per point, emit K=16 bf16 row-features (A) and col-features (B) so that
// dot(A_t, B_p) = |t|^2 + |p|^2 - 2 t.p  (hi/lo bf16 split, err ~2^-16 rel).
__global__ __launch_bounds__(256) void pack2_kernel(
    const float* __restrict__ target, const float* __restrict__ pred,
    short* __restrict__ tA, short* __restrict__ tB,
    short* __restrict__ pA, short* __restrict__ pB) {
    int gi = blockIdx.x * 256 + threadIdx.x;
    int second = gi >= NSET;
    int i = second ? gi - NSET : gi;
    const float* pts = second ? pred : target;
    short* A = second ? pA : tA;
    short* B = second ? pB : tB;

    float x = pts[3 * i + 0], y = pts[3 * i + 1], z = pts[3 * i + 2];
    float n2 = x * x + y * y + z * z;

    float xh = bfval(x), yh = bfval(y), zh = bfval(z), nh = bfval(n2);
    short xhb = bfbits(x), yhb = bfbits(y), zhb = bfbits(z), nhb = bfbits(n2);
    short xlb = bfbits(x - xh), ylb = bfbits(y - yh), zlb = bfbits(z - zh), nlb = bfbits(n2 - nh);
    short one = bfbits(1.0f);
    short mxh = bfbits(-2.0f * xh), myh = bfbits(-2.0f * yh), mzh = bfbits(-2.0f * zh);
    short mxl = bfbits(-2.0f * __bfloat162float(*(__hip_bfloat16*)&xlb));
    short myl = bfbits(-2.0f * __bfloat162float(*(__hip_bfloat16*)&ylb));
    short mzl = bfbits(-2.0f * __bfloat162float(*(__hip_bfloat16*)&zlb));

    // A k=0..15: [1,1,n2h,n2l, xh,xh,xl, yh,yh,yl, zh,zh,zl, 0,0,0]
    bf16x8 a0, a1, b0, b1;
    a0[0] = one; a0[1] = one; a0[2] = nhb; a0[3] = nlb;
    a0[4] = xhb; a0[5] = xhb; a0[6] = xlb; a0[7] = yhb;
    a1[0] = yhb; a1[1] = ylb; a1[2] = zhb; a1[3] = zhb;
    a1[4] = zlb; a1[5] = 0;   a1[6] = 0;   a1[7] = 0;
    // B k=0..15: [n2h,n2l,1,1, -2xh,-2xl,-2xh, -2yh,-2yl,-2yh, -2zh,-2zl,-2zh, 0,0,0]
    b0[0] = nhb; b0[1] = nlb; b0[2] = one; b0[3] = one;
    b0[4] = mxh; b0[5] = mxl; b0[6] = mxh; b0[7] = myh;
    b1[0] = myl; b1[1] = myh; b1[2] = mzh; b1[3] = mzl;
    b1[4] = mzh; b1[5] = 0;   b1[6] = 0;   b1[7] = 0;

    *reinterpret_cast<bf16x8*>(&A[(size_t)i * 16])     = a0;
    *reinterpret_cast<bf16x8*>(&A[(size_t)i * 16 + 8]) = a1;
    *reinterpret_cast<bf16x8*>(&B[(size_t)i * 16])     = b0;
    *reinterpret_cast<bf16x8*>(&B[(size_t)i * 16 + 8]) = b1;
}

// Grid 2048: direction x 8 batches x 32 row-groups x 4 col-quarters.
// Each wave: 2 row-frags (64 rows), 64 col-tiles in 32 pairs; min3-fold into
// 32 register row-min accumulators; butterfly + atomicMin epilogue.
// launch_bounds floor of 4 waves/EU (VGPR<=128; compiler uses ~48, so HW
// still fits 8 blocks/CU at runtime -- round 4's (256,8) forced VGPR=32 and
// spilled ~2 GB to scratch).
__global__ __launch_bounds__(256, 4) void chamfer_mfma_kernel(
    const short* __restrict__ targA, const short* __restrict__ targB,
    const short* __restrict__ predA, const short* __restrict__ predB,
    int* __restrict__ dist1, int* __restrict__ dist2)
{
    const int bid  = blockIdx.x;
    const int pass = bid >> 10;
    const int r10  = bid & 1023;
    const int b    = r10 >> 7;
    const int rest = r10 & 127;
    const int rowgrp = rest >> 2;       // 32 groups of 256 rows
    const int colq   = rest & 3;        // 4 quarters of 2048 cols
    const int wave = threadIdx.x >> 6;
    const int lane = threadIdx.x & 63;
    const int l31  = lane & 31, h = lane >> 5;

    const short* Af = pass ? predA : targA;
    const short* Bf = pass ? targB : predB;
    int* out = pass ? dist2 : dist1;

    const int row0 = rowgrp * 256 + wave * 64;
    const short* abase = Af + ((size_t)(b * NPTS + row0 + l31)) * 16 + h * 8;
    bf16x8 a0 = *reinterpret_cast<const bf16x8*>(abase);
    bf16x8 a1 = *reinterpret_cast<const bf16x8*>(abase + 32 * 16);

    const short* bptr = Bf + ((size_t)(b * NPTS + colq * 2048 + l31)) * 16 + h * 8;

    float acc0[16], acc1[16];
#pragma unroll
    for (int r = 0; r < 16; ++r) { acc0[r] = 3.4e38f; acc1[r] = 3.4e38f; }

    const f32x16 z = {0.f,0.f,0.f,0.f, 0.f,0.f,0.f,0.f, 0.f,0.f,0.f,0.f, 0.f,0.f,0.f,0.f};

    bf16x8 bA = *reinterpret_cast<const bf16x8*>(bptr);
    bf16x8 bB = *reinterpret_cast<const bf16x8*>(bptr + 512);

    for (int it = 0; it < 31; ++it) {
        bf16x8 nA = *reinterpret_cast<const bf16x8*>(bptr + 1024);
        bf16x8 nB = *reinterpret_cast<const bf16x8*>(bptr + 1536);

        f32x16 c0a = __builtin_amdgcn_mfma_f32_32x32x16_bf16(a0, bA, z, 0, 0, 0);
        f32x16 c0b = __builtin_amdgcn_mfma_f32_32x32x16_bf16(a0, bB, z, 0, 0, 0);
#pragma unroll
        for (int r = 0; r < 16; ++r)
            acc0[r] = fminf(acc0[r], fminf(c0a[r], c0b[r]));  // -> v_min3_f32

        f32x16 c1a = __builtin_amdgcn_mfma_f32_32x32x16_bf16(a1, bA, z, 0, 0, 0);
        f32x16 c1b = __builtin_amdgcn_mfma_f32_32x32x16_bf16(a1, bB, z, 0, 0, 0);
#pragma unroll
        for (int r = 0; r < 16; ++r)
            acc1[r] = fminf(acc1[r], fminf(c1a[r], c1b[r]));

        bA = nA; bB = nB;
        bptr += 1024;
    }
    {   // peeled last pair (no prefetch)
        f32x16 c0a = __builtin_amdgcn_mfma_f32_32x32x16_bf16(a0, bA, z, 0, 0, 0);
        f32x16 c0b = __builtin_amdgcn_mfma_f32_32x32x16_bf16(a0, bB, z, 0, 0, 0);
#pragma unroll
        for (int r = 0; r < 16; ++r)
            acc0[r] = fminf(acc0[r], fminf(c0a[r], c0b[r]));
        f32x16 c1a = __builtin_amdgcn_mfma_f32_32x32x16_bf16(a1, bA, z, 0, 0, 0);
        f32x16 c1b = __builtin_amdgcn_mfma_f32_32x32x16_bf16(a1, bB, z, 0, 0, 0);
#pragma unroll
        for (int r = 0; r < 16; ++r)
            acc1[r] = fminf(acc1[r], fminf(c1a[r], c1b[r]));
    }

    // butterfly min over the 32 cols held in each half's lanes
#pragma unroll
    for (int r = 0; r < 16; ++r) {
        float v0 = acc0[r], v1 = acc1[r];
#pragma unroll
        for (int s = 1; s < 32; s <<= 1) {
            v0 = fminf(v0, __shfl_xor(v0, s));
            v1 = fminf(v1, __shfl_xor(v1, s));
        }
        acc0[r] = v0; acc1[r] = v1;
    }

    if (l31 == 0) {
        int* ob = out + b * NPTS + row0;
#pragma unroll
        for (int r = 0; r < 16; ++r) {
            int rr = (r & 3) + 8 * (r >> 2) + 4 * h;  // verified C layout (m74/m101)
            // clamp >=0 so positive-float bit order == int order for atomicMin
            atomicMin(&ob[rr],      __float_as_int(fmaxf(acc0[r], 0.0f)));
            atomicMin(&ob[32 + rr], __float_as_int(fmaxf(acc1[r], 0.0f)));
        }
    }
}

__global__ __launch_bounds__(256) void reduce_kernel(const int* __restrict__ mins,
                                                     float* __restrict__ out) {
    int i = blockIdx.x * 256 + threadIdx.x;
    float v = __int_as_float(mins[i]) * (1.0f / (float)NSET);
#pragma unroll
    for (int o = 32; o > 0; o >>= 1) v += __shfl_down(v, o);
    if ((threadIdx.x & 63) == 0) atomicAdd(out, v);
}

extern "C" void kernel_launch(void* const* d_in, const int* in_sizes, int n_in,
                              void* d_out, int out_size, void* d_ws, size_t ws_size,
                              hipStream_t stream) {
    const float* pred   = (const float*)d_in[0];   // [8,8192,3]
    const float* target = (const float*)d_in[1];   // [8,8192,3]
    float* out = (float*)d_out;

    char* ws = (char*)d_ws;
    int* dist1 = (int*)ws;                           // 65536 ints (float bits)
    int* dist2 = dist1 + NSET;                       // 65536 ints
    short* tA = (short*)(ws + (size_t)2 * NSET * 4); // each 2 MB
    short* tB = tA + (size_t)NSET * 16;
    short* pA = tB + (size_t)NSET * 16;
    short* pB = pA + (size_t)NSET * 16;

    hipMemsetAsync(dist1, 0x7F, (size_t)2 * NSET * 4, stream);  // +huge float
    hipMemsetAsync(out, 0, sizeof(float), stream);

    pack2_kernel<<<2 * NSET / 256, 256, 0, stream>>>(target, pred, tA, tB, pA, pB);

    chamfer_mfma_kernel<<<2048, 256, 0, stream>>>(tA, tB, pA, pB, dist1, dist2);

    reduce_kernel<<<2 * NSET / 256, 256, 0, stream>>>(dist1, out);
}

// Round 6
// 71.470 us; speedup vs baseline: 6.3665x; 1.3143x over previous
//
#include <hip/hip_runtime.h>
#include <hip/hip_bf16.h>

typedef short bf16x8 __attribute__((ext_vector_type(8)));
typedef float f32x16 __attribute__((ext_vector_type(16)));

#define NB 8
#define NPTS 8192
#define NSET (NB * NPTS)

static __device__ __forceinline__ short bfbits(float x) {
    __hip_bfloat16 h = __float2bfloat16(x);  // RNE
    return *reinterpret_cast<short*>(&h);
}
static __device__ __forceinline__ float bfval(float x) {
    __hip_bfloat16 h = __float2bfloat16(x);
    return __bfloat162float(h);
}

// Per point, emit K=16 bf16 row-features (A) and col-features (B) so that
// dot(A_t, B_p) = |t|^2 + |p|^2 - 2 t.p  (hi/lo bf16 split, err ~2^-16 rel).
__global__ __launch_bounds__(256) void pack2_kernel(
    const float* __restrict__ target, const float* __restrict__ pred,
    short* __restrict__ tA, short* __restrict__ tB,
    short* __restrict__ pA, short* __restrict__ pB) {
    int gi = blockIdx.x * 256 + threadIdx.x;
    int second = gi >= NSET;
    int i = second ? gi - NSET : gi;
    const float* pts = second ? pred : target;
    short* A = second ? pA : tA;
    short* B = second ? pB : tB;

    float x = pts[3 * i + 0], y = pts[3 * i + 1], z = pts[3 * i + 2];
    float n2 = x * x + y * y + z * z;

    float xh = bfval(x), yh = bfval(y), zh = bfval(z), nh = bfval(n2);
    short xhb = bfbits(x), yhb = bfbits(y), zhb = bfbits(z), nhb = bfbits(n2);
    short xlb = bfbits(x - xh), ylb = bfbits(y - yh), zlb = bfbits(z - zh), nlb = bfbits(n2 - nh);
    short one = bfbits(1.0f);
    short mxh = bfbits(-2.0f * xh), myh = bfbits(-2.0f * yh), mzh = bfbits(-2.0f * zh);
    short mxl = bfbits(-2.0f * __bfloat162float(*(__hip_bfloat16*)&xlb));
    short myl = bfbits(-2.0f * __bfloat162float(*(__hip_bfloat16*)&ylb));
    short mzl = bfbits(-2.0f * __bfloat162float(*(__hip_bfloat16*)&zlb));

    // A k=0..15: [1,1,n2h,n2l, xh,xh,xl, yh,yh,yl, zh,zh,zl, 0,0,0]
    bf16x8 a0, a1, b0, b1;
    a0[0] = one; a0[1] = one; a0[2] = nhb; a0[3] = nlb;
    a0[4] = xhb; a0[5] = xhb; a0[6] = xlb; a0[7] = yhb;
    a1[0] = yhb; a1[1] = ylb; a1[2] = zhb; a1[3] = zhb;
    a1[4] = zlb; a1[5] = 0;   a1[6] = 0;   a1[7] = 0;
    // B k=0..15: [n2h,n2l,1,1, -2xh,-2xl,-2xh, -2yh,-2yl,-2yh, -2zh,-2zl,-2zh, 0,0,0]
    b0[0] = nhb; b0[1] = nlb; b0[2] = one; b0[3] = one;
    b0[4] = mxh; b0[5] = mxl; b0[6] = mxh; b0[7] = myh;
    b1[0] = myl; b1[1] = myh; b1[2] = mzh; b1[3] = mzl;
    b1[4] = mzh; b1[5] = 0;   b1[6] = 0;   b1[7] = 0;

    *reinterpret_cast<bf16x8*>(&A[(size_t)i * 16])     = a0;
    *reinterpret_cast<bf16x8*>(&A[(size_t)i * 16 + 8]) = a1;
    *reinterpret_cast<bf16x8*>(&B[(size_t)i * 16])     = b0;
    *reinterpret_cast<bf16x8*>(&B[(size_t)i * 16 + 8]) = b1;
}

// Grid 2048: direction x 8 batches x 64 rowgroups(128 rows) x 2 col-halves.
// ONE row-frag per wave (32 rows) -> per-wave register state ~95 total
// (acc16 + C-pair 32 + B cur/prefetch 32 + A 4 + addr) so HW fits 5 waves/SIMD
// (r3-r5 were capped at 3 by the 2-rowfrag variant's ~144 unified regs).
__global__ __launch_bounds__(256, 4) void chamfer_mfma_kernel(
    const short* __restrict__ targA, const short* __restrict__ targB,
    const short* __restrict__ predA, const short* __restrict__ predB,
    int* __restrict__ dist1, int* __restrict__ dist2)
{
    const int bid  = blockIdx.x;
    const int pass = bid >> 10;
    const int r10  = bid & 1023;
    const int b    = r10 >> 7;
    const int rest = r10 & 127;
    const int rowgrp  = rest >> 1;      // 64 groups of 128 rows
    const int colhalf = rest & 1;       // 2 halves of 4096 cols
    const int wave = threadIdx.x >> 6;
    const int lane = threadIdx.x & 63;
    const int l31  = lane & 31, h = lane >> 5;

    const short* Af = pass ? predA : targA;
    const short* Bf = pass ? targB : predB;
    int* out = pass ? dist2 : dist1;

    const int row0 = rowgrp * 128 + wave * 32;
    const short* abase = Af + ((size_t)(b * NPTS + row0 + l31)) * 16 + h * 8;
    bf16x8 a0 = *reinterpret_cast<const bf16x8*>(abase);

    const short* bptr = Bf + ((size_t)(b * NPTS + colhalf * 4096 + l31)) * 16 + h * 8;

    float acc[16];
#pragma unroll
    for (int r = 0; r < 16; ++r) acc[r] = 3.4e38f;

    const f32x16 z = {0.f,0.f,0.f,0.f, 0.f,0.f,0.f,0.f, 0.f,0.f,0.f,0.f, 0.f,0.f,0.f,0.f};

    bf16x8 bA = *reinterpret_cast<const bf16x8*>(bptr);
    bf16x8 bB = *reinterpret_cast<const bf16x8*>(bptr + 512);

    for (int it = 0; it < 63; ++it) {
        bf16x8 nA = *reinterpret_cast<const bf16x8*>(bptr + 1024);
        bf16x8 nB = *reinterpret_cast<const bf16x8*>(bptr + 1536);

        f32x16 ca = __builtin_amdgcn_mfma_f32_32x32x16_bf16(a0, bA, z, 0, 0, 0);
        f32x16 cb = __builtin_amdgcn_mfma_f32_32x32x16_bf16(a0, bB, z, 0, 0, 0);
#pragma unroll
        for (int r = 0; r < 16; ++r)
            acc[r] = fminf(fminf(acc[r], ca[r]), cb[r]);  // -> v_min3_f32

        bA = nA; bB = nB;
        bptr += 1024;
    }
    {   // peeled last pair (no prefetch)
        f32x16 ca = __builtin_amdgcn_mfma_f32_32x32x16_bf16(a0, bA, z, 0, 0, 0);
        f32x16 cb = __builtin_amdgcn_mfma_f32_32x32x16_bf16(a0, bB, z, 0, 0, 0);
#pragma unroll
        for (int r = 0; r < 16; ++r)
            acc[r] = fminf(fminf(acc[r], ca[r]), cb[r]);
    }

    // butterfly min over the 32 cols held in each half's lanes
#pragma unroll
    for (int r = 0; r < 16; ++r) {
        float v = acc[r];
#pragma unroll
        for (int s = 1; s < 32; s <<= 1) v = fminf(v, __shfl_xor(v, s));
        acc[r] = v;
    }

    if (l31 == 0) {
        int* ob = out + b * NPTS + row0;
#pragma unroll
        for (int r = 0; r < 16; ++r) {
            int rr = (r & 3) + 8 * (r >> 2) + 4 * h;  // verified C layout (m74/m101)
            // clamp >=0 so positive-float bit order == int order for atomicMin
            atomicMin(&ob[rr], __float_as_int(fmaxf(acc[r], 0.0f)));
        }
    }
}

// Grid-stride sum; one atomicAdd per block (round-5's 2048 same-address
// atomics serialized ~25us at L2).
__global__ __launch_bounds__(256) void reduce_kernel(const int* __restrict__ mins,
                                                     float* __restrict__ out) {
    __shared__ float part[4];
    const int stride = gridDim.x * 256;
    float v = 0.0f;
    for (int i = blockIdx.x * 256 + threadIdx.x; i < 2 * NSET; i += stride)
        v += __int_as_float(mins[i]);
    v *= (1.0f / (float)NSET);
#pragma unroll
    for (int o = 32; o > 0; o >>= 1) v += __shfl_down(v, o);
    if ((threadIdx.x & 63) == 0) part[threadIdx.x >> 6] = v;
    __syncthreads();
    if (threadIdx.x == 0)
        atomicAdd(out, part[0] + part[1] + part[2] + part[3]);
}

extern "C" void kernel_launch(void* const* d_in, const int* in_sizes, int n_in,
                              void* d_out, int out_size, void* d_ws, size_t ws_size,
                              hipStream_t stream) {
    const float* pred   = (const float*)d_in[0];   // [8,8192,3]
    const float* target = (const float*)d_in[1];   // [8,8192,3]
    float* out = (float*)d_out;

    char* ws = (char*)d_ws;
    int* dist1 = (int*)ws;                           // 65536 ints (float bits)
    int* dist2 = dist1 + NSET;                       // 65536 ints
    short* tA = (short*)(ws + (size_t)2 * NSET * 4); // each 2 MB
    short* tB = tA + (size_t)NSET * 16;
    short* pA = tB + (size_t)NSET * 16;
    short* pB = pA + (size_t)NSET * 16;

    hipMemsetAsync(dist1, 0x7F, (size_t)2 * NSET * 4, stream);  // +huge float
    hipMemsetAsync(out, 0, sizeof(float), stream);

    pack2_kernel<<<2 * NSET / 256, 256, 0, stream>>>(target, pred, tA, tB, pA, pB);

    chamfer_mfma_kernel<<<2048, 256, 0, stream>>>(tA, tB, pA, pB, dist1, dist2);

    reduce_kernel<<<128, 256, 0, stream>>>(dist1, out);
}

// Round 7
// 56.755 us; speedup vs baseline: 8.0172x; 1.2593x over previous
//
#include <hip/hip_runtime.h>
#include <hip/hip_bf16.h>

typedef short bf16x8 __attribute__((ext_vector_type(8)));
typedef float f32x16 __attribute__((ext_vector_type(16)));

#define NB 8
#define NPTS 8192
#define NSET (NB * NPTS)
#define CHUNK_BYTES 16384   // 16 col-tiles of 1KB
#define NCHUNK 8            // 128 tiles per col-half / 16

static __device__ __forceinline__ short bfbits(float x) {
    __hip_bfloat16 h = __float2bfloat16(x);  // RNE
    return *reinterpret_cast<short*>(&h);
}
static __device__ __forceinline__ float bfval(float x) {
    __hip_bfloat16 h = __float2bfloat16(x);
    return __bfloat162float(h);
}

// Per point, emit K=16 bf16 row-features (A) and col-features (B) so that
// dot(A_t, B_p) = |t|^2 + |p|^2 - 2 t.p  (hi/lo bf16 split; exact so far).
// B is written in FRAGMENT ORDER per 32-point tile: tile*1024B, khalf-major
// (khalf0 of 32 pts, then khalf1) so lane l reads its frag at tile*1024+l*16
// -> linear, conflict-free ds_read_b128 and linear global_load_lds staging.
__global__ __launch_bounds__(256) void pack2_kernel(
    const float* __restrict__ target, const float* __restrict__ pred,
    short* __restrict__ tA, short* __restrict__ tB,
    short* __restrict__ pA, short* __restrict__ pB) {
    int gi = blockIdx.x * 256 + threadIdx.x;
    int second = gi >= NSET;
    int i = second ? gi - NSET : gi;
    const float* pts = second ? pred : target;
    short* A = second ? pA : tA;
    short* B = second ? pB : tB;

    float x = pts[3 * i + 0], y = pts[3 * i + 1], z = pts[3 * i + 2];
    float n2 = x * x + y * y + z * z;

    float xh = bfval(x), yh = bfval(y), zh = bfval(z), nh = bfval(n2);
    short xhb = bfbits(x), yhb = bfbits(y), zhb = bfbits(z), nhb = bfbits(n2);
    short xlb = bfbits(x - xh), ylb = bfbits(y - yh), zlb = bfbits(z - zh), nlb = bfbits(n2 - nh);
    short one = bfbits(1.0f);
    short mxh = bfbits(-2.0f * xh), myh = bfbits(-2.0f * yh), mzh = bfbits(-2.0f * zh);
    short mxl = bfbits(-2.0f * __bfloat162float(*(__hip_bfloat16*)&xlb));
    short myl = bfbits(-2.0f * __bfloat162float(*(__hip_bfloat16*)&ylb));
    short mzl = bfbits(-2.0f * __bfloat162float(*(__hip_bfloat16*)&zlb));

    // A k=0..15: [1,1,n2h,n2l, xh,xh,xl, yh,yh,yl, zh,zh,zl, 0,0,0]
    bf16x8 a0, a1, b0, b1;
    a0[0] = one; a0[1] = one; a0[2] = nhb; a0[3] = nlb;
    a0[4] = xhb; a0[5] = xhb; a0[6] = xlb; a0[7] = yhb;
    a1[0] = yhb; a1[1] = ylb; a1[2] = zhb; a1[3] = zhb;
    a1[4] = zlb; a1[5] = 0;   a1[6] = 0;   a1[7] = 0;
    // B k=0..15: [n2h,n2l,1,1, -2xh,-2xl,-2xh, -2yh,-2yl,-2yh, -2zh,-2zl,-2zh, 0,0,0]
    b0[0] = nhb; b0[1] = nlb; b0[2] = one; b0[3] = one;
    b0[4] = mxh; b0[5] = mxl; b0[6] = mxh; b0[7] = myh;
    b1[0] = myl; b1[1] = myh; b1[2] = mzh; b1[3] = mzl;
    b1[4] = mzh; b1[5] = 0;   b1[6] = 0;   b1[7] = 0;

    *reinterpret_cast<bf16x8*>(&A[(size_t)i * 16])     = a0;
    *reinterpret_cast<bf16x8*>(&A[(size_t)i * 16 + 8]) = a1;

    int bb = i >> 13;                 // batch
    int pi = i & (NPTS - 1);
    int tile = pi >> 5, l = pi & 31;
    short* Bp = B + (size_t)bb * NPTS * 16 + tile * 512;
    *reinterpret_cast<bf16x8*>(Bp + l * 8)       = b0;   // khalf 0
    *reinterpret_cast<bf16x8*>(Bp + 256 + l * 8) = b1;   // khalf 1
}

// Stage one 16KB chunk (16 tiles) global->LDS. Each wave copies 4x1KB; LDS
// dest is wave-uniform base (+lane*16 added by HW); global src is per-lane.
static __device__ __forceinline__ void stage_chunk(char* ldsbase, const char* gsrc,
                                                   int wave, int lane) {
#pragma unroll
    for (int s = 0; s < 4; ++s) {
        int off = s * 4096 + wave * 1024;
        __builtin_amdgcn_global_load_lds(
            (const __attribute__((address_space(1))) unsigned int*)(gsrc + off + lane * 16),
            (__attribute__((address_space(3))) unsigned int*)(ldsbase + off),
            16, 0, 0);
    }
}

// lane-merge: combine two row-registers across lane-pairs (xor m); lanes with
// bit m==0 keep row u's min, bit m==1 keep row v's min; col coverage doubles.
#define MERGE(dst, u, v, m) {                       \
    float _own = (lane & (m)) ? (v) : (u);          \
    float _sel = (lane & (m)) ? (u) : (v);          \
    dst = fminf(_own, __shfl_xor(_sel, (m))); }

// Grid 1024: direction x 8 batches x 32 rowgroups(256 rows) x 2 col-halves.
// Block: 4 waves x 64 rows (R=2 row-frags). B staged in LDS (double-buffered
// 16KB chunks shared by all 4 waves): L2 traffic /4 vs r6, LDS pipe carries
// the 537MB fragment stream (~10us floor) instead of L2 (~31us floor at R=1).
__global__ __launch_bounds__(256, 4) void chamfer_mfma_kernel(
    const short* __restrict__ targA, const short* __restrict__ targB,
    const short* __restrict__ predA, const short* __restrict__ predB,
    int* __restrict__ dist1, int* __restrict__ dist2)
{
    __shared__ __align__(16) char smem[2][CHUNK_BYTES];

    const int bid  = blockIdx.x;
    const int pass = bid >> 9;
    const int b    = (bid >> 6) & 7;
    const int rowgrp  = (bid >> 1) & 31;   // 32 groups of 256 rows
    const int colhalf = bid & 1;           // 2 halves of 4096 cols
    const int wave = threadIdx.x >> 6;
    const int lane = threadIdx.x & 63;
    const int l31  = lane & 31, h = lane >> 5;

    const short* Af = pass ? predA : targA;
    const short* Bf = pass ? targB : predB;
    int* out = pass ? dist2 : dist1;

    const int row0 = rowgrp * 256 + wave * 64;
    const short* abase = Af + ((size_t)(b * NPTS + row0 + l31)) * 16 + h * 8;
    bf16x8 a0 = *reinterpret_cast<const bf16x8*>(abase);            // rows row0..+31
    bf16x8 a1 = *reinterpret_cast<const bf16x8*>(abase + 32 * 16);  // rows +32..+63

    // fragment-ordered B source for this block's col-half
    const char* bsrc = (const char*)Bf + (size_t)b * NPTS * 32 + (size_t)colhalf * 131072;

    float acc0[16], acc1[16];
#pragma unroll
    for (int r = 0; r < 16; ++r) { acc0[r] = 3.4e38f; acc1[r] = 3.4e38f; }

    const f32x16 z = {0.f,0.f,0.f,0.f, 0.f,0.f,0.f,0.f, 0.f,0.f,0.f,0.f, 0.f,0.f,0.f,0.f};

    stage_chunk(smem[0], bsrc, wave, lane);

    for (int c = 0; c < NCHUNK; ++c) {
        __syncthreads();   // chunk c staged (vmcnt drained); buffer c^1 free
        if (c + 1 < NCHUNK)
            stage_chunk(smem[(c + 1) & 1], bsrc + (size_t)(c + 1) * CHUNK_BYTES, wave, lane);
        const char* bufc = smem[c & 1];
#pragma unroll
        for (int t = 0; t < 16; t += 2) {
            bf16x8 bA = *reinterpret_cast<const bf16x8*>(bufc + t * 1024 + lane * 16);
            bf16x8 bB = *reinterpret_cast<const bf16x8*>(bufc + t * 1024 + 1024 + lane * 16);
            f32x16 ca = __builtin_amdgcn_mfma_f32_32x32x16_bf16(a0, bA, z, 0, 0, 0);
            f32x16 cb = __builtin_amdgcn_mfma_f32_32x32x16_bf16(a0, bB, z, 0, 0, 0);
#pragma unroll
            for (int r = 0; r < 16; ++r)
                acc0[r] = fminf(fminf(acc0[r], ca[r]), cb[r]);  // -> v_min3_f32
            f32x16 da = __builtin_amdgcn_mfma_f32_32x32x16_bf16(a1, bA, z, 0, 0, 0);
            f32x16 db = __builtin_amdgcn_mfma_f32_32x32x16_bf16(a1, bB, z, 0, 0, 0);
#pragma unroll
            for (int r = 0; r < 16; ++r)
                acc1[r] = fminf(fminf(acc1[r], da[r]), db[r]);
        }
    }

    // log-merge: 32 regs x 32-lane col-min -> each lane holds one row's min.
    // acc row map: row = (r&3) + 8*(r>>2) + 4*h (+32 for acc1).
#pragma unroll
    for (int k = 0; k < 8; ++k) { MERGE(acc0[k], acc0[2*k], acc0[2*k+1], 1); }
#pragma unroll
    for (int k = 0; k < 8; ++k) { MERGE(acc1[k], acc1[2*k], acc1[2*k+1], 1); }
#pragma unroll
    for (int k = 0; k < 4; ++k) { MERGE(acc0[k], acc0[2*k], acc0[2*k+1], 2); }
#pragma unroll
    for (int k = 0; k < 4; ++k) { MERGE(acc1[k], acc1[2*k], acc1[2*k+1], 2); }
#pragma unroll
    for (int k = 0; k < 2; ++k) { MERGE(acc0[k], acc0[2*k], acc0[2*k+1], 4); }
#pragma unroll
    for (int k = 0; k < 2; ++k) { MERGE(acc1[k], acc1[2*k], acc1[2*k+1], 4); }
    MERGE(acc0[0], acc0[0], acc0[1], 8);
    MERGE(acc1[0], acc1[0], acc1[1], 8);
    float fin;
    MERGE(fin, acc0[0], acc1[0], 16);
    // row(lane): lane bits {0,1}->row bits{0,1}, lane5->+4, lane2->+8,
    // lane3->+16, lane4->+32 (from merge schedule above)
    int row = (lane & 3) + 4 * ((lane >> 5) & 1) + 8 * ((lane >> 2) & 1)
            + 16 * ((lane >> 3) & 1) + 32 * ((lane >> 4) & 1);
    // clamp >=0 so positive-float bit order == int order for atomicMin
    atomicMin(&out[b * NPTS + row0 + row], __float_as_int(fmaxf(fin, 0.0f)));
}

// Grid-stride sum; one atomicAdd per block.
__global__ __launch_bounds__(256) void reduce_kernel(const int* __restrict__ mins,
                                                     float* __restrict__ out) {
    __shared__ float part[4];
    const int stride = gridDim.x * 256;
    float v = 0.0f;
    for (int i = blockIdx.x * 256 + threadIdx.x; i < 2 * NSET; i += stride)
        v += __int_as_float(mins[i]);
    v *= (1.0f / (float)NSET);
#pragma unroll
    for (int o = 32; o > 0; o >>= 1) v += __shfl_down(v, o);
    if ((threadIdx.x & 63) == 0) part[threadIdx.x >> 6] = v;
    __syncthreads();
    if (threadIdx.x == 0)
        atomicAdd(out, part[0] + part[1] + part[2] + part[3]);
}

extern "C" void kernel_launch(void* const* d_in, const int* in_sizes, int n_in,
                              void* d_out, int out_size, void* d_ws, size_t ws_size,
                              hipStream_t stream) {
    const float* pred   = (const float*)d_in[0];   // [8,8192,3]
    const float* target = (const float*)d_in[1];   // [8,8192,3]
    float* out = (float*)d_out;

    char* ws = (char*)d_ws;
    int* dist1 = (int*)ws;                           // 65536 ints (float bits)
    int* dist2 = dist1 + NSET;                       // 65536 ints
    short* tA = (short*)(ws + (size_t)2 * NSET * 4); // each 2 MB
    short* tB = tA + (size_t)NSET * 16;
    short* pA = tB + (size_t)NSET * 16;
    short* pB = pA + (size_t)NSET * 16;

    hipMemsetAsync(dist1, 0x7F, (size_t)2 * NSET * 4, stream);  // +huge float
    hipMemsetAsync(out, 0, sizeof(float), stream);

    pack2_kernel<<<2 * NSET / 256, 256, 0, stream>>>(target, pred, tA, tB, pA, pB);

    chamfer_mfma_kernel<<<1024, 256, 0, stream>>>(tA, tB, pA, pB, dist1, dist2);

    reduce_kernel<<<128, 256, 0, stream>>>(dist1, out);
}

// Round 8
// 48.637 us; speedup vs baseline: 9.3554x; 1.1669x over previous
//
#include <hip/hip_runtime.h>
#include <hip/hip_bf16.h>

typedef short bf16x8 __attribute__((ext_vector_type(8)));
typedef float f32x16 __attribute__((ext_vector_type(16)));

#define NB 8
#define NPTS 8192
#define NSET (NB * NPTS)
#define CHUNK_BYTES 16384   // 16 col-tiles of 1KB
#define NCHUNK 16           // full 8192 cols = 256 tiles = 16 chunks

static __device__ __forceinline__ short bfbits(float x) {
    __hip_bfloat16 h = __float2bfloat16(x);  // RNE
    return *reinterpret_cast<short*>(&h);
}
static __device__ __forceinline__ float bfval(float x) {
    __hip_bfloat16 h = __float2bfloat16(x);
    return __bfloat162float(h);
}

// Per point, emit K=16 bf16 row-features (A) and col-features (B) so that
// dot(A_t, B_p) = |t|^2 + |p|^2 - 2 t.p  (hi/lo bf16 split).
// B is written in FRAGMENT ORDER per 32-point tile (tile*1024B, khalf-major)
// so staging and ds_read_b128 are linear lane*16 -> conflict-free.
__global__ __launch_bounds__(256) void pack2_kernel(
    const float* __restrict__ target, const float* __restrict__ pred,
    short* __restrict__ tA, short* __restrict__ tB,
    short* __restrict__ pA, short* __restrict__ pB) {
    int gi = blockIdx.x * 256 + threadIdx.x;
    int second = gi >= NSET;
    int i = second ? gi - NSET : gi;
    const float* pts = second ? pred : target;
    short* A = second ? pA : tA;
    short* B = second ? pB : tB;

    float x = pts[3 * i + 0], y = pts[3 * i + 1], z = pts[3 * i + 2];
    float n2 = x * x + y * y + z * z;

    float xh = bfval(x), yh = bfval(y), zh = bfval(z), nh = bfval(n2);
    short xhb = bfbits(x), yhb = bfbits(y), zhb = bfbits(z), nhb = bfbits(n2);
    short xlb = bfbits(x - xh), ylb = bfbits(y - yh), zlb = bfbits(z - zh), nlb = bfbits(n2 - nh);
    short one = bfbits(1.0f);
    short mxh = bfbits(-2.0f * xh), myh = bfbits(-2.0f * yh), mzh = bfbits(-2.0f * zh);
    short mxl = bfbits(-2.0f * __bfloat162float(*(__hip_bfloat16*)&xlb));
    short myl = bfbits(-2.0f * __bfloat162float(*(__hip_bfloat16*)&ylb));
    short mzl = bfbits(-2.0f * __bfloat162float(*(__hip_bfloat16*)&zlb));

    // A k=0..15: [1,1,n2h,n2l, xh,xh,xl, yh,yh,yl, zh,zh,zl, 0,0,0]
    bf16x8 a0, a1, b0, b1;
    a0[0] = one; a0[1] = one; a0[2] = nhb; a0[3] = nlb;
    a0[4] = xhb; a0[5] = xhb; a0[6] = xlb; a0[7] = yhb;
    a1[0] = yhb; a1[1] = ylb; a1[2] = zhb; a1[3] = zhb;
    a1[4] = zlb; a1[5] = 0;   a1[6] = 0;   a1[7] = 0;
    // B k=0..15: [n2h,n2l,1,1, -2xh,-2xl,-2xh, -2yh,-2yl,-2yh, -2zh,-2zl,-2zh, 0,0,0]
    b0[0] = nhb; b0[1] = nlb; b0[2] = one; b0[3] = one;
    b0[4] = mxh; b0[5] = mxl; b0[6] = mxh; b0[7] = myh;
    b1[0] = myl; b1[1] = myh; b1[2] = mzh; b1[3] = mzl;
    b1[4] = mzh; b1[5] = 0;   b1[6] = 0;   b1[7] = 0;

    *reinterpret_cast<bf16x8*>(&A[(size_t)i * 16])     = a0;
    *reinterpret_cast<bf16x8*>(&A[(size_t)i * 16 + 8]) = a1;

    int bb = i >> 13;                 // batch
    int pi = i & (NPTS - 1);
    int tile = pi >> 5, l = pi & 31;
    short* Bp = B + (size_t)bb * NPTS * 16 + tile * 512;
    *reinterpret_cast<bf16x8*>(Bp + l * 8)       = b0;   // khalf 0
    *reinterpret_cast<bf16x8*>(Bp + 256 + l * 8) = b1;   // khalf 1
}

// Stage one 16KB chunk (16 tiles) global->LDS; each wave copies 4x1KB.
static __device__ __forceinline__ void stage_chunk(char* ldsbase, const char* gsrc,
                                                   int wave, int lane) {
#pragma unroll
    for (int s = 0; s < 4; ++s) {
        int off = s * 4096 + wave * 1024;
        __builtin_amdgcn_global_load_lds(
            (const __attribute__((address_space(1))) unsigned int*)(gsrc + off + lane * 16),
            (__attribute__((address_space(3))) unsigned int*)(ldsbase + off),
            16, 0, 0);
    }
}

// lane-merge: combine two row-registers across lane-pairs (xor m).
#define MERGE(dst, u, v, m) {                       \
    float _own = (lane & (m)) ? (v) : (u);          \
    float _sel = (lane & (m)) ? (u) : (v);          \
    dst = fminf(_own, __shfl_xor(_sel, (m))); }

// Grid 512: direction x 8 batches x 32 rowgroups(256 rows). Each block
// streams ALL 8192 cols (16 dbuf LDS chunks) -> block-exact row mins ->
// no atomics, no init. Epilogue folds rowmins to ONE partial sum per block.
__global__ __launch_bounds__(256, 4) void chamfer_mfma_kernel(
    const short* __restrict__ targA, const short* __restrict__ targB,
    const short* __restrict__ predA, const short* __restrict__ predB,
    float* __restrict__ partials)
{
    __shared__ __align__(16) char smem[2][CHUNK_BYTES];
    __shared__ float wpart[4];

    const int bid  = blockIdx.x;
    const int pass = bid >> 8;             // 0: rows=target, 1: rows=pred
    const int b    = (bid >> 5) & 7;
    const int rowgrp = bid & 31;           // 32 groups of 256 rows
    const int wave = threadIdx.x >> 6;
    const int lane = threadIdx.x & 63;
    const int l31  = lane & 31, h = lane >> 5;

    const short* Af = pass ? predA : targA;
    const short* Bf = pass ? targB : predB;

    const int row0 = rowgrp * 256 + wave * 64;
    const short* abase = Af + ((size_t)(b * NPTS + row0 + l31)) * 16 + h * 8;
    bf16x8 a0 = *reinterpret_cast<const bf16x8*>(abase);            // rows +0..31
    bf16x8 a1 = *reinterpret_cast<const bf16x8*>(abase + 32 * 16);  // rows +32..63

    const char* bsrc = (const char*)Bf + (size_t)b * NPTS * 32;  // 256KB, frag-ordered

    float acc0[16], acc1[16];
#pragma unroll
    for (int r = 0; r < 16; ++r) { acc0[r] = 3.4e38f; acc1[r] = 3.4e38f; }

    const f32x16 z = {0.f,0.f,0.f,0.f, 0.f,0.f,0.f,0.f, 0.f,0.f,0.f,0.f, 0.f,0.f,0.f,0.f};

    stage_chunk(smem[0], bsrc, wave, lane);

    for (int c = 0; c < NCHUNK; ++c) {
        __syncthreads();   // chunk c staged (vmcnt drained at barrier)
        if (c + 1 < NCHUNK)
            stage_chunk(smem[(c + 1) & 1], bsrc + (size_t)(c + 1) * CHUNK_BYTES, wave, lane);
        const char* bufc = smem[c & 1];
#pragma unroll
        for (int t = 0; t < 16; t += 2) {
            bf16x8 bA = *reinterpret_cast<const bf16x8*>(bufc + t * 1024 + lane * 16);
            bf16x8 bB = *reinterpret_cast<const bf16x8*>(bufc + t * 1024 + 1024 + lane * 16);
            f32x16 ca = __builtin_amdgcn_mfma_f32_32x32x16_bf16(a0, bA, z, 0, 0, 0);
            f32x16 cb = __builtin_amdgcn_mfma_f32_32x32x16_bf16(a0, bB, z, 0, 0, 0);
#pragma unroll
            for (int r = 0; r < 16; ++r)
                acc0[r] = fminf(fminf(acc0[r], ca[r]), cb[r]);  // -> v_min3_f32
            f32x16 da = __builtin_amdgcn_mfma_f32_32x32x16_bf16(a1, bA, z, 0, 0, 0);
            f32x16 db = __builtin_amdgcn_mfma_f32_32x32x16_bf16(a1, bB, z, 0, 0, 0);
#pragma unroll
            for (int r = 0; r < 16; ++r)
                acc1[r] = fminf(fminf(acc1[r], da[r]), db[r]);
        }
    }

    // log-merge: 32 regs x 32-lane col-min -> each lane holds one row's min.
#pragma unroll
    for (int k = 0; k < 8; ++k) { MERGE(acc0[k], acc0[2*k], acc0[2*k+1], 1); }
#pragma unroll
    for (int k = 0; k < 8; ++k) { MERGE(acc1[k], acc1[2*k], acc1[2*k+1], 1); }
#pragma unroll
    for (int k = 0; k < 4; ++k) { MERGE(acc0[k], acc0[2*k], acc0[2*k+1], 2); }
#pragma unroll
    for (int k = 0; k < 4; ++k) { MERGE(acc1[k], acc1[2*k], acc1[2*k+1], 2); }
#pragma unroll
    for (int k = 0; k < 2; ++k) { MERGE(acc0[k], acc0[2*k], acc0[2*k+1], 4); }
#pragma unroll
    for (int k = 0; k < 2; ++k) { MERGE(acc1[k], acc1[2*k], acc1[2*k+1], 4); }
    MERGE(acc0[0], acc0[0], acc0[1], 8);
    MERGE(acc1[0], acc1[0], acc1[1], 8);
    float fin;
    MERGE(fin, acc0[0], acc1[0], 16);   // lane now holds min over ALL 8192 cols
    // (row identity no longer needed -- we only need the sum of row-mins)

    // wave sum of 64 distinct row-mins, then block sum -> one partial
    float s = fin;
#pragma unroll
    for (int o = 32; o > 0; o >>= 1) s += __shfl_xor(s, o);
    if (lane == 0) wpart[wave] = s;
    __syncthreads();
    if (threadIdx.x == 0)
        partials[bid] = wpart[0] + wpart[1] + wpart[2] + wpart[3];
}

// Single block: sum 512 block-partials, scale, store (no atomics/init).
__global__ __launch_bounds__(512) void final_kernel(const float* __restrict__ partials,
                                                    float* __restrict__ out) {
    __shared__ float wpart[8];
    float v = partials[threadIdx.x];
#pragma unroll
    for (int o = 32; o > 0; o >>= 1) v += __shfl_xor(v, o);
    if ((threadIdx.x & 63) == 0) wpart[threadIdx.x >> 6] = v;
    __syncthreads();
    if (threadIdx.x == 0) {
        float s = 0.f;
#pragma unroll
        for (int w = 0; w < 8; ++w) s += wpart[w];
        out[0] = s * (1.0f / (float)NSET);
    }
}

extern "C" void kernel_launch(void* const* d_in, const int* in_sizes, int n_in,
                              void* d_out, int out_size, void* d_ws, size_t ws_size,
                              hipStream_t stream) {
    const float* pred   = (const float*)d_in[0];   // [8,8192,3]
    const float* target = (const float*)d_in[1];   // [8,8192,3]
    float* out = (float*)d_out;

    char* ws = (char*)d_ws;
    float* partials = (float*)ws;                    // 512 floats
    short* tA = (short*)(ws + 4096);                 // each 2 MB
    short* tB = tA + (size_t)NSET * 16;
    short* pA = tB + (size_t)NSET * 16;
    short* pB = pA + (size_t)NSET * 16;

    pack2_kernel<<<2 * NSET / 256, 256, 0, stream>>>(target, pred, tA, tB, pA, pB);

    chamfer_mfma_kernel<<<512, 256, 0, stream>>>(tA, tB, pA, pB, partials);

    final_kernel<<<1, 512, 0, stream>>>(partials, out);
}